// Round 2
// baseline (4412.230 us; speedup 1.0000x reference)
//
#include <hip/hip_runtime.h>
#include <math.h>

#define H 32
#define LAGN 50

__device__ __forceinline__ float sigmoidf_(float x){
  return __frcp_rn(1.0f + __expf(-x));
}
__device__ __forceinline__ float tanhf_(float x){
  // (e^{2x}-1)/(e^{2x}+1) computed stably for both tails
  return 1.0f - 2.0f*__frcp_rn(__expf(2.0f*x) + 1.0f);
}

// ---------------- LSTM + time-attention + fc, one thread per node ----------
// 64-thread blocks, launch_bounds(64,2): VGPR cap 256 so the h/c/S/hn state
// (~150 live VGPRs) stays in registers -- at 188 (256-thread default) it
// spilled to scratch (12.5 GB WRITE_SIZE observed in round 1).
__global__ __launch_bounds__(64, 2) void k_lstm(
    const float* __restrict__ yx,    // [N,50]
    const float* __restrict__ w_ih,  // [128]
    const float* __restrict__ w_hh,  // [128,32]
    const float* __restrict__ b_ih,  // [128]
    const float* __restrict__ b_hh,  // [128]
    const float* __restrict__ att_W, // [50,32]
    const float* __restrict__ fc_W,  // [32,32]
    const float* __restrict__ fc_b,  // [32]
    float* __restrict__ x1,          // [N,32] out
    int N)
{
  int n = blockIdx.x*blockDim.x + threadIdx.x;
  if (n >= N) return;

  float h[H], c[H], S[H];
  #pragma unroll
  for (int j=0;j<H;j++){ h[j]=0.f; c[j]=0.f; S[j]=0.f; }
  float m = -1e30f, Z = 0.f;

  const float* yxr = yx + (size_t)n*LAGN;

  #pragma unroll 1
  for (int t=0;t<LAGN;t++){
    float xt = yxr[t];
    float hn[H];
    float st = 0.f;
    #pragma unroll
    for (int j=0;j<H;j++){
      float ai = b_ih[0*H+j] + b_hh[0*H+j] + w_ih[0*H+j]*xt;
      float af = b_ih[1*H+j] + b_hh[1*H+j] + w_ih[1*H+j]*xt;
      float ag = b_ih[2*H+j] + b_hh[2*H+j] + w_ih[2*H+j]*xt;
      float ao = b_ih[3*H+j] + b_hh[3*H+j] + w_ih[3*H+j]*xt;
      #pragma unroll
      for (int k=0;k<H;k++){
        float hk = h[k];
        ai += w_hh[(0*H+j)*H+k]*hk;
        af += w_hh[(1*H+j)*H+k]*hk;
        ag += w_hh[(2*H+j)*H+k]*hk;
        ao += w_hh[(3*H+j)*H+k]*hk;
      }
      float iv = sigmoidf_(ai);
      float fv = sigmoidf_(af);
      float gv = tanhf_(ag);
      float ov = sigmoidf_(ao);
      float cv = fv*c[j] + iv*gv;
      c[j] = cv;
      float hv = ov*tanhf_(cv);
      hn[j] = hv;
      st += hv * att_W[t*H+j];
    }
    // online softmax over t (exact, flash-style)
    float mn = fmaxf(m, st);
    float sc = __expf(m - mn);
    float p  = __expf(st - mn);
    Z = Z*sc + p;
    #pragma unroll
    for (int j=0;j<H;j++){
      S[j] = S[j]*sc + p*hn[j];
      h[j] = hn[j];
    }
    m = mn;
  }

  float invZ = __frcp_rn(Z);
  #pragma unroll
  for (int j=0;j<H;j++) S[j] *= invZ;   // pooled

  float* xo = x1 + (size_t)n*H;
  #pragma unroll
  for (int jj=0;jj<H;jj++){
    float a = fc_b[jj];
    #pragma unroll
    for (int k=0;k<H;k++) a += S[k]*fc_W[k*H+jj];
    xo[jj] = fmaxf(a, 0.f);
  }
}

// ---------------- GCN helpers ------------------------------------------------
__global__ void k_deg_init(float* __restrict__ deg, int N){
  int i = blockIdx.x*blockDim.x + threadIdx.x;
  if (i < N) deg[i] = 1.0f;   // self-loop weight
}

__global__ void k_deg_edges(const int* __restrict__ ei, const float* __restrict__ ew,
                            float* __restrict__ deg, int E){
  int e = blockIdx.x*blockDim.x + threadIdx.x;
  if (e < E) atomicAdd(&deg[ei[E+e]], ew[e]);   // dst row = ei[1]
}

__global__ void k_dis(float* __restrict__ deg, int N){
  int i = blockIdx.x*blockDim.x + threadIdx.x;
  if (i < N) deg[i] = __frcp_rn(sqrtf(deg[i]));  // deg >= 1 always
}

__global__ void k_norm(const int* __restrict__ ei, const float* __restrict__ ew,
                       const float* __restrict__ dis, float* __restrict__ nrm, int E){
  int e = blockIdx.x*blockDim.x + threadIdx.x;
  if (e < E) nrm[e] = dis[ei[e]]*ew[e]*dis[ei[E+e]];
}

// xw = x @ W ; out = (1/deg)*xw + b   (self-loop contribution folded in)
__global__ __launch_bounds__(256) void k_xw(
    const float* __restrict__ x, const float* __restrict__ W,
    const float* __restrict__ b, const float* __restrict__ dis,
    float* __restrict__ xw, float* __restrict__ out, int N)
{
  int n = blockIdx.x*blockDim.x + threadIdx.x;
  if (n >= N) return;
  float xv[H];
  const float4* xr = (const float4*)(x + (size_t)n*H);
  #pragma unroll
  for (int q=0;q<H/4;q++){
    float4 v = xr[q];
    xv[4*q+0]=v.x; xv[4*q+1]=v.y; xv[4*q+2]=v.z; xv[4*q+3]=v.w;
  }
  float d = dis[n];
  float sn = d*d;               // = 1/deg
  float* xwr = xw + (size_t)n*H;
  float* outr = out + (size_t)n*H;
  #pragma unroll
  for (int j=0;j<H;j++){
    float a = 0.f;
    #pragma unroll
    for (int k=0;k<H;k++) a += xv[k]*W[k*H+j];
    xwr[j]  = a;
    outr[j] = sn*a + b[j];
  }
}

// out[dst] += norm[e] * xw[src] ; 8 threads per edge, 4 channels each
__global__ __launch_bounds__(256) void k_edge(
    const int* __restrict__ ei, const float* __restrict__ nrm,
    const float* __restrict__ xw, float* __restrict__ out, int E)
{
  int tid = blockIdx.x*blockDim.x + threadIdx.x;
  int e = tid >> 3;
  if (e >= E) return;
  int q = (tid & 7) * 4;
  int s = ei[e];
  int d = ei[E+e];
  float nm = nrm[e];
  float4 v = *(const float4*)(xw + (size_t)s*H + q);
  float* o = out + (size_t)d*H + q;
  atomicAdd(o+0, nm*v.x);
  atomicAdd(o+1, nm*v.y);
  atomicAdd(o+2, nm*v.z);
  atomicAdd(o+3, nm*v.w);
}

__global__ void k_final(const float* __restrict__ x2, const float* __restrict__ nx,
                        const float* __restrict__ lw, const float* __restrict__ lb,
                        float* __restrict__ out, int N)
{
  int n = blockIdx.x*blockDim.x + threadIdx.x;
  if (n >= N) return;
  float a = lb[0];
  const float* xr = x2 + (size_t)n*H;
  #pragma unroll
  for (int j=0;j<H;j++) a += xr[j]*lw[j];
  const float* nr = nx + (size_t)n*4;
  #pragma unroll
  for (int f=0;f<4;f++) a += nr[f]*lw[H+f];
  out[n] = fmaxf(a, 0.f);
}

extern "C" void kernel_launch(void* const* d_in, const int* in_sizes, int n_in,
                              void* d_out, int out_size, void* d_ws, size_t ws_size,
                              hipStream_t stream) {
  const float* node_x   = (const float*)d_in[0];
  const float* node_yx  = (const float*)d_in[1];
  const int*   edge_idx = (const int*)  d_in[2];
  const float* edge_w   = (const float*)d_in[3];
  const float* w_ih     = (const float*)d_in[4];
  const float* w_hh     = (const float*)d_in[5];
  const float* b_ih     = (const float*)d_in[6];
  const float* b_hh     = (const float*)d_in[7];
  const float* att_W    = (const float*)d_in[8];
  const float* fc_W     = (const float*)d_in[9];
  const float* fc_b     = (const float*)d_in[10];
  const float* gcn1_W   = (const float*)d_in[11];
  const float* gcn1_b   = (const float*)d_in[12];
  const float* gcn2_W   = (const float*)d_in[13];
  const float* gcn2_b   = (const float*)d_in[14];
  const float* lin_W    = (const float*)d_in[15];
  const float* lin_b    = (const float*)d_in[16];
  float* out = (float*)d_out;

  int N = in_sizes[0] / 4;     // node_x is [N,4]
  int E = in_sizes[3];         // edge_weight is [E]

  float* ws = (float*)d_ws;
  float* x1  = ws;                       // [N,32]  (reused as out2)
  float* xw  = ws + (size_t)N*H;         // [N,32]
  float* o1  = ws + 2*(size_t)N*H;       // [N,32]
  float* deg = ws + 3*(size_t)N*H;       // [N]   (becomes dis)
  float* nrm = deg + N;                  // [E]

  dim3 blk(256);
  int gN  = (N + 255) / 256;
  int gE  = (E + 255) / 256;
  int gE8 = (int)(((size_t)E*8 + 255) / 256);
  int gL  = (N + 63) / 64;               // 64-thread blocks for k_lstm

  // 1. LSTM + attention + fc
  k_lstm<<<gL, dim3(64), 0, stream>>>(node_yx, w_ih, w_hh, b_ih, b_hh,
                                      att_W, fc_W, fc_b, x1, N);
  // 2. degrees (self-loop = 1.0 init), then dis = deg^-1/2, then edge norms
  k_deg_init<<<gN, blk, 0, stream>>>(deg, N);
  k_deg_edges<<<gE, blk, 0, stream>>>(edge_idx, edge_w, deg, E);
  k_dis<<<gN, blk, 0, stream>>>(deg, N);
  k_norm<<<gE, blk, 0, stream>>>(edge_idx, edge_w, deg, nrm, E);
  // 3. GCN layer 1
  k_xw  <<<gN, blk, 0, stream>>>(x1, gcn1_W, gcn1_b, deg, xw, o1, N);
  k_edge<<<gE8, blk, 0, stream>>>(edge_idx, nrm, xw, o1, E);
  // 4. GCN layer 2 (out2 overwrites x1 buffer)
  k_xw  <<<gN, blk, 0, stream>>>(o1, gcn2_W, gcn2_b, deg, xw, x1, N);
  k_edge<<<gE8, blk, 0, stream>>>(edge_idx, nrm, xw, x1, E);
  // 5. final linear + relu
  k_final<<<gN, blk, 0, stream>>>(x1, node_x, lin_W, lin_b, out, N);
}

// Round 3
// 4209.755 us; speedup vs baseline: 1.0481x; 1.0481x over previous
//
#include <hip/hip_runtime.h>
#include <math.h>

#define H 32
#define LAGN 50

__device__ __forceinline__ float sigmoidf_(float x){
  return __frcp_rn(1.0f + __expf(-x));
}
__device__ __forceinline__ float tanhf_(float x){
  return 1.0f - 2.0f*__frcp_rn(__expf(2.0f*x) + 1.0f);
}

// One LSTM cell column J (literal!) so every array index is compile-time
// constant -> SROA keeps h/c/S/hn in VGPRs (round 2: runtime-indexed arrays
// went to scratch, 1.2 GB of h[k] re-reads at 21:1 read:write).
#define J_STEP(J) { \
    float ai = b_ih[0*H+(J)] + b_hh[0*H+(J)] + w_ih[0*H+(J)]*xt; \
    float af = b_ih[1*H+(J)] + b_hh[1*H+(J)] + w_ih[1*H+(J)]*xt; \
    float ag = b_ih[2*H+(J)] + b_hh[2*H+(J)] + w_ih[2*H+(J)]*xt; \
    float ao = b_ih[3*H+(J)] + b_hh[3*H+(J)] + w_ih[3*H+(J)]*xt; \
    const float* wr0 = w_hh + (0*H+(J))*H; \
    const float* wr1 = w_hh + (1*H+(J))*H; \
    const float* wr2 = w_hh + (2*H+(J))*H; \
    const float* wr3 = w_hh + (3*H+(J))*H; \
    _Pragma("unroll") \
    for (int k=0;k<H;k++){ \
      float hk = h[k]; \
      ai += wr0[k]*hk; af += wr1[k]*hk; ag += wr2[k]*hk; ao += wr3[k]*hk; \
    } \
    float iv = sigmoidf_(ai); \
    float fv = sigmoidf_(af); \
    float gv = tanhf_(ag); \
    float ov = sigmoidf_(ao); \
    float cv = fv*c[(J)] + iv*gv; \
    c[(J)] = cv; \
    float hv = ov*tanhf_(cv); \
    hn[(J)] = hv; \
    st += hv * att_W[t*H+(J)]; \
  }

// ---------------- LSTM + time-attention + fc, one thread per node ----------
__global__ __launch_bounds__(64, 1) void k_lstm(
    const float* __restrict__ yx,    // [N,50]
    const float* __restrict__ w_ih,  // [128]
    const float* __restrict__ w_hh,  // [128,32]
    const float* __restrict__ b_ih,  // [128]
    const float* __restrict__ b_hh,  // [128]
    const float* __restrict__ att_W, // [50,32]
    const float* __restrict__ fc_W,  // [32,32]
    const float* __restrict__ fc_b,  // [32]
    float* __restrict__ x1,          // [N,32] out
    int N)
{
  int n = blockIdx.x*blockDim.x + threadIdx.x;
  if (n >= N) return;

  float h[H], c[H], S[H];
  #pragma unroll
  for (int j=0;j<H;j++){ h[j]=0.f; c[j]=0.f; S[j]=0.f; }
  float m = -1e30f, Z = 0.f;

  const float* yxr = yx + (size_t)n*LAGN;
  float xtbuf = yxr[0];

  #pragma unroll 1
  for (int t=0;t<LAGN;t++){
    float xt = xtbuf;
    if (t+1 < LAGN) xtbuf = yxr[t+1];   // prefetch next step's input
    float hn[H];
    float st = 0.f;

    J_STEP(0)  J_STEP(1)  J_STEP(2)  J_STEP(3)
    J_STEP(4)  J_STEP(5)  J_STEP(6)  J_STEP(7)
    J_STEP(8)  J_STEP(9)  J_STEP(10) J_STEP(11)
    J_STEP(12) J_STEP(13) J_STEP(14) J_STEP(15)
    J_STEP(16) J_STEP(17) J_STEP(18) J_STEP(19)
    J_STEP(20) J_STEP(21) J_STEP(22) J_STEP(23)
    J_STEP(24) J_STEP(25) J_STEP(26) J_STEP(27)
    J_STEP(28) J_STEP(29) J_STEP(30) J_STEP(31)

    // online softmax over t (exact, flash-style)
    float mn = fmaxf(m, st);
    float sc = __expf(m - mn);
    float p  = __expf(st - mn);
    Z = Z*sc + p;
    #pragma unroll
    for (int j=0;j<H;j++){
      S[j] = S[j]*sc + p*hn[j];
      h[j] = hn[j];
    }
    m = mn;
  }

  float invZ = __frcp_rn(Z);
  #pragma unroll
  for (int j=0;j<H;j++) S[j] *= invZ;   // pooled

  float* xo = x1 + (size_t)n*H;
  #pragma unroll
  for (int jj=0;jj<H;jj++){
    float a = fc_b[jj];
    #pragma unroll
    for (int k=0;k<H;k++) a += S[k]*fc_W[k*H+jj];
    xo[jj] = fmaxf(a, 0.f);
  }
}

// ---------------- GCN helpers ------------------------------------------------
__global__ void k_deg_init(float* __restrict__ deg, int N){
  int i = blockIdx.x*blockDim.x + threadIdx.x;
  if (i < N) deg[i] = 1.0f;   // self-loop weight
}

__global__ void k_deg_edges(const int* __restrict__ ei, const float* __restrict__ ew,
                            float* __restrict__ deg, int E){
  int e = blockIdx.x*blockDim.x + threadIdx.x;
  if (e < E) atomicAdd(&deg[ei[E+e]], ew[e]);   // dst row = ei[1]
}

__global__ void k_dis(float* __restrict__ deg, int N){
  int i = blockIdx.x*blockDim.x + threadIdx.x;
  if (i < N) deg[i] = __frcp_rn(sqrtf(deg[i]));  // deg >= 1 always
}

__global__ void k_norm(const int* __restrict__ ei, const float* __restrict__ ew,
                       const float* __restrict__ dis, float* __restrict__ nrm, int E){
  int e = blockIdx.x*blockDim.x + threadIdx.x;
  if (e < E) nrm[e] = dis[ei[e]]*ew[e]*dis[ei[E+e]];
}

// xw = x @ W ; out = (1/deg)*xw + b   (self-loop contribution folded in)
__global__ __launch_bounds__(256) void k_xw(
    const float* __restrict__ x, const float* __restrict__ W,
    const float* __restrict__ b, const float* __restrict__ dis,
    float* __restrict__ xw, float* __restrict__ out, int N)
{
  int n = blockIdx.x*blockDim.x + threadIdx.x;
  if (n >= N) return;
  float xv[H];
  const float4* xr = (const float4*)(x + (size_t)n*H);
  #pragma unroll
  for (int q=0;q<H/4;q++){
    float4 v = xr[q];
    xv[4*q+0]=v.x; xv[4*q+1]=v.y; xv[4*q+2]=v.z; xv[4*q+3]=v.w;
  }
  float d = dis[n];
  float sn = d*d;               // = 1/deg
  float* xwr = xw + (size_t)n*H;
  float* outr = out + (size_t)n*H;
  #pragma unroll
  for (int j=0;j<H;j++){
    float a = 0.f;
    #pragma unroll
    for (int k=0;k<H;k++) a += xv[k]*W[k*H+j];
    xwr[j]  = a;
    outr[j] = sn*a + b[j];
  }
}

// out[dst] += norm[e] * xw[src] ; 8 threads per edge, 4 channels each
__global__ __launch_bounds__(256) void k_edge(
    const int* __restrict__ ei, const float* __restrict__ nrm,
    const float* __restrict__ xw, float* __restrict__ out, int E)
{
  int tid = blockIdx.x*blockDim.x + threadIdx.x;
  int e = tid >> 3;
  if (e >= E) return;
  int q = (tid & 7) * 4;
  int s = ei[e];
  int d = ei[E+e];
  float nm = nrm[e];
  float4 v = *(const float4*)(xw + (size_t)s*H + q);
  float* o = out + (size_t)d*H + q;
  atomicAdd(o+0, nm*v.x);
  atomicAdd(o+1, nm*v.y);
  atomicAdd(o+2, nm*v.z);
  atomicAdd(o+3, nm*v.w);
}

__global__ void k_final(const float* __restrict__ x2, const float* __restrict__ nx,
                        const float* __restrict__ lw, const float* __restrict__ lb,
                        float* __restrict__ out, int N)
{
  int n = blockIdx.x*blockDim.x + threadIdx.x;
  if (n >= N) return;
  float a = lb[0];
  const float* xr = x2 + (size_t)n*H;
  #pragma unroll
  for (int j=0;j<H;j++) a += xr[j]*lw[j];
  const float* nr = nx + (size_t)n*4;
  #pragma unroll
  for (int f=0;f<4;f++) a += nr[f]*lw[H+f];
  out[n] = fmaxf(a, 0.f);
}

extern "C" void kernel_launch(void* const* d_in, const int* in_sizes, int n_in,
                              void* d_out, int out_size, void* d_ws, size_t ws_size,
                              hipStream_t stream) {
  const float* node_x   = (const float*)d_in[0];
  const float* node_yx  = (const float*)d_in[1];
  const int*   edge_idx = (const int*)  d_in[2];
  const float* edge_w   = (const float*)d_in[3];
  const float* w_ih     = (const float*)d_in[4];
  const float* w_hh     = (const float*)d_in[5];
  const float* b_ih     = (const float*)d_in[6];
  const float* b_hh     = (const float*)d_in[7];
  const float* att_W    = (const float*)d_in[8];
  const float* fc_W     = (const float*)d_in[9];
  const float* fc_b     = (const float*)d_in[10];
  const float* gcn1_W   = (const float*)d_in[11];
  const float* gcn1_b   = (const float*)d_in[12];
  const float* gcn2_W   = (const float*)d_in[13];
  const float* gcn2_b   = (const float*)d_in[14];
  const float* lin_W    = (const float*)d_in[15];
  const float* lin_b    = (const float*)d_in[16];
  float* out = (float*)d_out;

  int N = in_sizes[0] / 4;     // node_x is [N,4]
  int E = in_sizes[3];         // edge_weight is [E]

  float* ws = (float*)d_ws;
  float* x1  = ws;                       // [N,32]  (reused as out2)
  float* xw  = ws + (size_t)N*H;         // [N,32]
  float* o1  = ws + 2*(size_t)N*H;       // [N,32]
  float* deg = ws + 3*(size_t)N*H;       // [N]   (becomes dis)
  float* nrm = deg + N;                  // [E]

  dim3 blk(256);
  int gN  = (N + 255) / 256;
  int gE  = (E + 255) / 256;
  int gE8 = (int)(((size_t)E*8 + 255) / 256);
  int gL  = (N + 63) / 64;               // 64-thread blocks for k_lstm

  // 1. LSTM + attention + fc
  k_lstm<<<gL, dim3(64), 0, stream>>>(node_yx, w_ih, w_hh, b_ih, b_hh,
                                      att_W, fc_W, fc_b, x1, N);
  // 2. degrees (self-loop = 1.0 init), then dis = deg^-1/2, then edge norms
  k_deg_init<<<gN, blk, 0, stream>>>(deg, N);
  k_deg_edges<<<gE, blk, 0, stream>>>(edge_idx, edge_w, deg, E);
  k_dis<<<gN, blk, 0, stream>>>(deg, N);
  k_norm<<<gE, blk, 0, stream>>>(edge_idx, edge_w, deg, nrm, E);
  // 3. GCN layer 1
  k_xw  <<<gN, blk, 0, stream>>>(x1, gcn1_W, gcn1_b, deg, xw, o1, N);
  k_edge<<<gE8, blk, 0, stream>>>(edge_idx, nrm, xw, o1, E);
  // 4. GCN layer 2 (out2 overwrites x1 buffer)
  k_xw  <<<gN, blk, 0, stream>>>(o1, gcn2_W, gcn2_b, deg, xw, x1, N);
  k_edge<<<gE8, blk, 0, stream>>>(edge_idx, nrm, xw, x1, E);
  // 5. final linear + relu
  k_final<<<gN, blk, 0, stream>>>(x1, node_x, lin_W, lin_b, out, N);
}

// Round 4
// 3153.680 us; speedup vs baseline: 1.3991x; 1.3349x over previous
//
#include <hip/hip_runtime.h>
#include <math.h>

#define H 32
#define LAGN 50
#define NPB 64   // nodes per block (one per lane; 4 waves split the 32 J-columns)

__device__ __forceinline__ float rcp_(float x){ return __builtin_amdgcn_rcpf(x); }
__device__ __forceinline__ float sigmoidf_(float x){ return rcp_(1.0f + __expf(-x)); }
__device__ __forceinline__ float tanhf_(float x){ return 1.0f - 2.0f*rcp_(__expf(2.0f*x) + 1.0f); }

// Cooperative LSTM: block = 256 threads = 64 nodes (lane) x 4 waves (J-groups).
// Why: one-thread-per-node yields only 1563 waves total (0.75-1.5/SIMD) ->
// latency-bound at 9% occupancy (rounds 1-3 all ~2850us). Splitting J across
// 4 waves quadruples wave count and cuts per-wave weight traffic to 4KB/t,
// while LDS double-buffering keeps it to ONE barrier per timestep.
__global__ __launch_bounds__(256, 4) void k_lstm(
    const float* __restrict__ yx,    // [N,50]
    const float* __restrict__ w_ih,  // [128]
    const float* __restrict__ w_hh,  // [128,32]
    const float* __restrict__ b_ih,  // [128]
    const float* __restrict__ b_hh,  // [128]
    const float* __restrict__ att_W, // [50,32]
    const float* __restrict__ fc_W,  // [32,32]
    const float* __restrict__ fc_b,  // [32]
    float* __restrict__ x1,          // [N,32] out
    int N)
{
  // +1 pad: read stride 33 -> bank (lane+k)%32 -> 2-way aliasing only (free)
  __shared__ float h_lds[2][NPB][H+1];
  __shared__ __align__(16) float st_lds[2][NPB][4];

  const int lane = threadIdx.x & 63;
  // readfirstlane: guarantee the backend sees J0 (and all weight addresses
  // derived from it) as wave-uniform -> s_load path for w_hh/b/att/fc.
  const int J0 = __builtin_amdgcn_readfirstlane((threadIdx.x >> 6) * 8);
  const int n  = blockIdx.x*NPB + lane;
  const int nc = n < N ? n : N-1;   // clamp loads; store guarded at the end

  // zero initial h buffer
  for (int i = threadIdx.x; i < NPB*(H+1); i += 256)
    ((float*)h_lds[0])[i] = 0.f;
  __syncthreads();

  float c[8], S[8];
  #pragma unroll
  for (int jj=0;jj<8;jj++){ c[jj]=0.f; S[jj]=0.f; }
  float m = -1e30f, Z = 0.f;

  const float* yxr = yx + (size_t)nc*LAGN;
  float xtbuf = yxr[0];

  int cur = 0;
  #pragma unroll 1
  for (int t=0;t<LAGN;t++){
    float xt = xtbuf;
    if (t+1 < LAGN) xtbuf = yxr[t+1];

    // (a) pull this node's full h vector from LDS
    float hk[H];
    #pragma unroll
    for (int k=0;k<H;k++) hk[k] = h_lds[cur][lane][k];

    // (b) this wave's 8 J-columns
    float st = 0.f;
    float hn[8];
    #pragma unroll
    for (int jj=0;jj<8;jj++){
      const int j = J0 + jj;
      float ai = b_ih[0*H+j] + b_hh[0*H+j] + w_ih[0*H+j]*xt;
      float af = b_ih[1*H+j] + b_hh[1*H+j] + w_ih[1*H+j]*xt;
      float ag = b_ih[2*H+j] + b_hh[2*H+j] + w_ih[2*H+j]*xt;
      float ao = b_ih[3*H+j] + b_hh[3*H+j] + w_ih[3*H+j]*xt;
      const float* r0 = w_hh + (0*H+j)*H;
      const float* r1 = w_hh + (1*H+j)*H;
      const float* r2 = w_hh + (2*H+j)*H;
      const float* r3 = w_hh + (3*H+j)*H;
      #pragma unroll
      for (int k=0;k<H;k++){
        float hv = hk[k];
        ai += r0[k]*hv; af += r1[k]*hv; ag += r2[k]*hv; ao += r3[k]*hv;
      }
      float iv = sigmoidf_(ai);
      float fv = sigmoidf_(af);
      float gv = tanhf_(ag);
      float ov = sigmoidf_(ao);
      float cv = fv*c[jj] + iv*gv;
      c[jj] = cv;
      float hv2 = ov*tanhf_(cv);
      hn[jj] = hv2;
      st += hv2 * att_W[t*H + j];
    }

    const int nxt = cur ^ 1;
    // (c) publish hn slice + partial attention score
    #pragma unroll
    for (int jj=0;jj<8;jj++) h_lds[nxt][lane][J0+jj] = hn[jj];
    st_lds[nxt][lane][threadIdx.x>>6] = st;
    // (d) single barrier per timestep (double-buffer removes RW hazard)
    __syncthreads();
    // (e) total score; replicated (bit-identical) softmax state per wave
    float4 sp = *(const float4*)&st_lds[nxt][lane][0];
    float stot = ((sp.x + sp.y) + sp.z) + sp.w;
    float mn = fmaxf(m, stot);
    float sc = __expf(m - mn);
    float p  = __expf(stot - mn);
    Z = Z*sc + p;
    #pragma unroll
    for (int jj=0;jj<8;jj++) S[jj] = S[jj]*sc + p*hn[jj];
    m = mn;
    cur = nxt;
  }

  float invZ = rcp_(Z);
  #pragma unroll
  for (int jj=0;jj<8;jj++) S[jj] *= invZ;   // pooled slice

  // stage pooled vector so every wave can read all 32 components
  __syncthreads();
  #pragma unroll
  for (int jj=0;jj<8;jj++) h_lds[0][lane][J0+jj] = S[jj];
  __syncthreads();
  float Sv[H];
  #pragma unroll
  for (int k=0;k<H;k++) Sv[k] = h_lds[0][lane][k];

  if (n < N){
    float* xo = x1 + (size_t)n*H;
    #pragma unroll
    for (int jj=0;jj<8;jj++){
      const int oc = J0 + jj;
      float a = fc_b[oc];
      #pragma unroll
      for (int k=0;k<H;k++) a += Sv[k]*fc_W[k*H+oc];
      xo[oc] = fmaxf(a, 0.f);
    }
  }
}

// ---------------- GCN helpers (unchanged this round) -----------------------
__global__ void k_deg_init(float* __restrict__ deg, int N){
  int i = blockIdx.x*blockDim.x + threadIdx.x;
  if (i < N) deg[i] = 1.0f;   // self-loop weight
}

__global__ void k_deg_edges(const int* __restrict__ ei, const float* __restrict__ ew,
                            float* __restrict__ deg, int E){
  int e = blockIdx.x*blockDim.x + threadIdx.x;
  if (e < E) atomicAdd(&deg[ei[E+e]], ew[e]);   // dst row = ei[1]
}

__global__ void k_dis(float* __restrict__ deg, int N){
  int i = blockIdx.x*blockDim.x + threadIdx.x;
  if (i < N) deg[i] = __frcp_rn(sqrtf(deg[i]));  // deg >= 1 always
}

__global__ void k_norm(const int* __restrict__ ei, const float* __restrict__ ew,
                       const float* __restrict__ dis, float* __restrict__ nrm, int E){
  int e = blockIdx.x*blockDim.x + threadIdx.x;
  if (e < E) nrm[e] = dis[ei[e]]*ew[e]*dis[ei[E+e]];
}

__global__ __launch_bounds__(256) void k_xw(
    const float* __restrict__ x, const float* __restrict__ W,
    const float* __restrict__ b, const float* __restrict__ dis,
    float* __restrict__ xw, float* __restrict__ out, int N)
{
  int n = blockIdx.x*blockDim.x + threadIdx.x;
  if (n >= N) return;
  float xv[H];
  const float4* xr = (const float4*)(x + (size_t)n*H);
  #pragma unroll
  for (int q=0;q<H/4;q++){
    float4 v = xr[q];
    xv[4*q+0]=v.x; xv[4*q+1]=v.y; xv[4*q+2]=v.z; xv[4*q+3]=v.w;
  }
  float d = dis[n];
  float sn = d*d;               // = 1/deg
  float* xwr = xw + (size_t)n*H;
  float* outr = out + (size_t)n*H;
  #pragma unroll
  for (int j=0;j<H;j++){
    float a = 0.f;
    #pragma unroll
    for (int k=0;k<H;k++) a += xv[k]*W[k*H+j];
    xwr[j]  = a;
    outr[j] = sn*a + b[j];
  }
}

__global__ __launch_bounds__(256) void k_edge(
    const int* __restrict__ ei, const float* __restrict__ nrm,
    const float* __restrict__ xw, float* __restrict__ out, int E)
{
  int tid = blockIdx.x*blockDim.x + threadIdx.x;
  int e = tid >> 3;
  if (e >= E) return;
  int q = (tid & 7) * 4;
  int s = ei[e];
  int d = ei[E+e];
  float nm = nrm[e];
  float4 v = *(const float4*)(xw + (size_t)s*H + q);
  float* o = out + (size_t)d*H + q;
  atomicAdd(o+0, nm*v.x);
  atomicAdd(o+1, nm*v.y);
  atomicAdd(o+2, nm*v.z);
  atomicAdd(o+3, nm*v.w);
}

__global__ void k_final(const float* __restrict__ x2, const float* __restrict__ nx,
                        const float* __restrict__ lw, const float* __restrict__ lb,
                        float* __restrict__ out, int N)
{
  int n = blockIdx.x*blockDim.x + threadIdx.x;
  if (n >= N) return;
  float a = lb[0];
  const float* xr = x2 + (size_t)n*H;
  #pragma unroll
  for (int j=0;j<H;j++) a += xr[j]*lw[j];
  const float* nr = nx + (size_t)n*4;
  #pragma unroll
  for (int f=0;f<4;f++) a += nr[f]*lw[H+f];
  out[n] = fmaxf(a, 0.f);
}

extern "C" void kernel_launch(void* const* d_in, const int* in_sizes, int n_in,
                              void* d_out, int out_size, void* d_ws, size_t ws_size,
                              hipStream_t stream) {
  const float* node_x   = (const float*)d_in[0];
  const float* node_yx  = (const float*)d_in[1];
  const int*   edge_idx = (const int*)  d_in[2];
  const float* edge_w   = (const float*)d_in[3];
  const float* w_ih     = (const float*)d_in[4];
  const float* w_hh     = (const float*)d_in[5];
  const float* b_ih     = (const float*)d_in[6];
  const float* b_hh     = (const float*)d_in[7];
  const float* att_W    = (const float*)d_in[8];
  const float* fc_W     = (const float*)d_in[9];
  const float* fc_b     = (const float*)d_in[10];
  const float* gcn1_W   = (const float*)d_in[11];
  const float* gcn1_b   = (const float*)d_in[12];
  const float* gcn2_W   = (const float*)d_in[13];
  const float* gcn2_b   = (const float*)d_in[14];
  const float* lin_W    = (const float*)d_in[15];
  const float* lin_b    = (const float*)d_in[16];
  float* out = (float*)d_out;

  int N = in_sizes[0] / 4;     // node_x is [N,4]
  int E = in_sizes[3];         // edge_weight is [E]

  float* ws = (float*)d_ws;
  float* x1  = ws;                       // [N,32]  (reused as out2)
  float* xw  = ws + (size_t)N*H;         // [N,32]
  float* o1  = ws + 2*(size_t)N*H;       // [N,32]
  float* deg = ws + 3*(size_t)N*H;       // [N]   (becomes dis)
  float* nrm = deg + N;                  // [E]

  dim3 blk(256);
  int gN  = (N + 255) / 256;
  int gE  = (E + 255) / 256;
  int gE8 = (int)(((size_t)E*8 + 255) / 256);
  int gL  = (N + NPB - 1) / NPB;         // 64 nodes per 256-thread block

  // 1. LSTM + attention + fc (cooperative 4-wave blocks)
  k_lstm<<<gL, blk, 0, stream>>>(node_yx, w_ih, w_hh, b_ih, b_hh,
                                 att_W, fc_W, fc_b, x1, N);
  // 2. degrees (self-loop = 1.0 init), then dis = deg^-1/2, then edge norms
  k_deg_init<<<gN, blk, 0, stream>>>(deg, N);
  k_deg_edges<<<gE, blk, 0, stream>>>(edge_idx, edge_w, deg, E);
  k_dis<<<gN, blk, 0, stream>>>(deg, N);
  k_norm<<<gE, blk, 0, stream>>>(edge_idx, edge_w, deg, nrm, E);
  // 3. GCN layer 1
  k_xw  <<<gN, blk, 0, stream>>>(x1, gcn1_W, gcn1_b, deg, xw, o1, N);
  k_edge<<<gE8, blk, 0, stream>>>(edge_idx, nrm, xw, o1, E);
  // 4. GCN layer 2 (out2 overwrites x1 buffer)
  k_xw  <<<gN, blk, 0, stream>>>(o1, gcn2_W, gcn2_b, deg, xw, x1, N);
  k_edge<<<gE8, blk, 0, stream>>>(edge_idx, nrm, xw, x1, E);
  // 5. final linear + relu
  k_final<<<gN, blk, 0, stream>>>(x1, node_x, lin_W, lin_b, out, N);
}

// Round 5
// 1813.612 us; speedup vs baseline: 2.4328x; 1.7389x over previous
//
#include <hip/hip_runtime.h>
#include <math.h>

#define H 32
#define LAGN 50

typedef float f32x4 __attribute__((ext_vector_type(4)));
typedef short bf16x8 __attribute__((ext_vector_type(8)));

__device__ __forceinline__ float rcp_(float x){ return __builtin_amdgcn_rcpf(x); }
__device__ __forceinline__ float sigmoidf_(float x){ return rcp_(1.0f + __expf(-x)); }
__device__ __forceinline__ float tanhf_(float x){ return 1.0f - 2.0f*rcp_(__expf(2.0f*x) + 1.0f); }

// round-to-nearest-even fp32 -> bf16 (bit math, matches MFMA bf16 semantics)
__device__ __forceinline__ unsigned short bfhi(float f){
  unsigned u = __float_as_uint(f);
  return (unsigned short)((u + 0x7FFFu + ((u>>16)&1u)) >> 16);
}
__device__ __forceinline__ float bf2f(unsigned short h){
  return __uint_as_float(((unsigned)h)<<16);
}

// ---------------- MFMA LSTM + time-attention + fc ---------------------------
// One wave = 16 nodes. Gate matvec G[16,128] = h[16,32] @ w_hh^T done as
// 8 MFMA 16x16x32 tiles with bf16x3 error compensation (fp32-grade accuracy).
// w_hh lives in VGPRs as B-fragments for all 50 steps (zero per-t weight
// traffic -- round 4's bottleneck). Everything is wave-local: NO barriers.
// Layouts (gfx950, m89-verified C map): C/D: col=lane&15, row=(lane>>4)*4+reg.
// A/B: M-or-N index = lane&15, k = (lane>>4)*8 + i (symmetric A/B => any
// common k-permutation error cancels in the dot product).
__global__ __launch_bounds__(64, 2) void k_lstm(
    const float* __restrict__ yx,    // [N,50]
    const float* __restrict__ w_ih,  // [128]
    const float* __restrict__ w_hh,  // [128,32]
    const float* __restrict__ b_ih,  // [128]
    const float* __restrict__ b_hh,  // [128]
    const float* __restrict__ att_W, // [50,32]
    const float* __restrict__ fc_W,  // [32,32]
    const float* __restrict__ fc_b,  // [32]
    float* __restrict__ x1,          // [N,32] out
    int N)
{
  __shared__ float hs[16*36];        // h staging [16 rows][36] (pad: 16B-align + 2-way banks)
  const int l  = threadIdx.x;        // 0..63
  const int q  = l >> 4;             // 0..3
  const int cl = l & 15;             // 0..15
  const int nb = blockIdx.x * 16;    // first node of this wave

  // ---- B fragments of w_hh (hi/lo bf16), held in VGPRs for all t ----
  // B[k][col] = w_hh[col*H + k]; lane: col = 16T+cl, k = 8q+i (contiguous)
  bf16x8 Bhi[8], Blo[8];
  #pragma unroll
  for (int T=0; T<8; ++T){
    const float* p = w_hh + (size_t)(16*T + cl)*H + 8*q;
    f32x4 w0 = *(const f32x4*)p;
    f32x4 w1 = *(const f32x4*)(p+4);
    #pragma unroll
    for (int i=0;i<4;i++){
      unsigned short hh0 = bfhi(w0[i]);
      Bhi[T][i]   = (short)hh0;  Blo[T][i]   = (short)bfhi(w0[i] - bf2f(hh0));
      unsigned short hh1 = bfhi(w1[i]);
      Bhi[T][4+i] = (short)hh1;  Blo[T][4+i] = (short)bfhi(w1[i] - bf2f(hh1));
    }
  }

  // per-lane gate-column constants (col = 16T+cl)
  float wihv[8], bsv[8];
  #pragma unroll
  for (int T=0;T<8;T++){
    int colg = 16*T + cl;
    wihv[T] = w_ih[colg];
    bsv[T]  = b_ih[colg] + b_hh[colg];
  }

  // zero-init h staging (single wave: lockstep, no barrier needed)
  #pragma unroll
  for (int i=l; i<16*36; i+=64) hs[i] = 0.f;

  float cst[4][2], Sv[4][2], mv[4], Zv[4];
  #pragma unroll
  for (int idx=0;idx<4;idx++){
    mv[idx] = -1e30f; Zv[idx] = 0.f;
    cst[idx][0]=0.f; cst[idx][1]=0.f; Sv[idx][0]=0.f; Sv[idx][1]=0.f;
  }

  // prefetch t=0 inputs
  float xtc[4], atc[2];
  #pragma unroll
  for (int idx=0;idx<4;idx++){
    int r = nb + 4*q + idx; if (r >= N) r = N-1;
    xtc[idx] = yx[(size_t)r*LAGN];
  }
  atc[0] = att_W[cl];  atc[1] = att_W[cl+16];

  #pragma unroll 1
  for (int t=0;t<LAGN;t++){
    // prefetch next step's xt / att row
    int tn = (t+1<LAGN) ? t+1 : t;
    float xtn[4], atn[2];
    #pragma unroll
    for (int idx=0;idx<4;idx++){
      int r = nb + 4*q + idx; if (r >= N) r = N-1;
      xtn[idx] = yx[(size_t)r*LAGN + tn];
    }
    atn[0] = att_W[tn*H + cl];  atn[1] = att_W[tn*H + cl + 16];

    // A fragment: row = cl, k = 8q..8q+8 (16B-aligned thanks to pad 36)
    f32x4 a0 = *(const f32x4*)&hs[36*cl + 8*q];
    f32x4 a1 = *(const f32x4*)&hs[36*cl + 8*q + 4];
    bf16x8 Ahi, Alo;
    #pragma unroll
    for (int i=0;i<4;i++){
      unsigned short h0 = bfhi(a0[i]);
      Ahi[i]   = (short)h0;  Alo[i]   = (short)bfhi(a0[i] - bf2f(h0));
      unsigned short h1 = bfhi(a1[i]);
      Ahi[4+i] = (short)h1;  Alo[4+i] = (short)bfhi(a1[i] - bf2f(h1));
    }

    // 8 tiles x 3 MFMAs (bf16x3): G = h @ w_hh^T in fp32-grade precision
    f32x4 C[8];
    #pragma unroll
    for (int T=0;T<8;T++){
      f32x4 z = {0.f,0.f,0.f,0.f};
      z = __builtin_amdgcn_mfma_f32_16x16x32_bf16(Ahi, Blo[T], z, 0,0,0);
      z = __builtin_amdgcn_mfma_f32_16x16x32_bf16(Alo, Bhi[T], z, 0,0,0);
      z = __builtin_amdgcn_mfma_f32_16x16x32_bf16(Ahi, Bhi[T], z, 0,0,0);
      C[T] = z;
    }

    // gates + state update; cell (row=4q+idx, j=cl+16jh)
    float stp[4];
    float hv[4][2];
    #pragma unroll
    for (int idx=0; idx<4; ++idx){
      stp[idx] = 0.f;
      #pragma unroll
      for (int jh=0; jh<2; ++jh){
        float gi = C[jh][idx]   + xtc[idx]*wihv[jh]   + bsv[jh];
        float gf = C[2+jh][idx] + xtc[idx]*wihv[2+jh] + bsv[2+jh];
        float gg = C[4+jh][idx] + xtc[idx]*wihv[4+jh] + bsv[4+jh];
        float go = C[6+jh][idx] + xtc[idx]*wihv[6+jh] + bsv[6+jh];
        float iv = sigmoidf_(gi), fv = sigmoidf_(gf);
        float gv = tanhf_(gg),    ov = sigmoidf_(go);
        float cn = fv*cst[idx][jh] + iv*gv;
        cst[idx][jh] = cn;
        float hh = ov*tanhf_(cn);
        hv[idx][jh] = hh;
        stp[idx] += hh * atc[jh];
        hs[36*(4*q+idx) + cl + 16*jh] = hh;   // publish for next-t A-frag
      }
    }

    // attention score: reduce over the 16 lanes of this q-group (butterfly)
    #pragma unroll
    for (int mask=1; mask<16; mask<<=1){
      #pragma unroll
      for (int idx=0;idx<4;idx++)
        stp[idx] += __shfl_xor(stp[idx], mask);
    }

    // online softmax (state replicated bit-identically across the 16 lanes)
    #pragma unroll
    for (int idx=0;idx<4;idx++){
      float mn = fmaxf(mv[idx], stp[idx]);
      float sc = __expf(mv[idx] - mn);
      float p  = __expf(stp[idx] - mn);
      Zv[idx] = Zv[idx]*sc + p;
      Sv[idx][0] = Sv[idx][0]*sc + p*hv[idx][0];
      Sv[idx][1] = Sv[idx][1]*sc + p*hv[idx][1];
      mv[idx] = mn;
    }
    #pragma unroll
    for (int idx=0;idx<4;idx++) xtc[idx] = xtn[idx];
    atc[0] = atn[0]; atc[1] = atn[1];
  }

  // pooled = S/Z -> staging -> A-fragment
  #pragma unroll
  for (int idx=0;idx<4;idx++){
    float iz = rcp_(Zv[idx]);
    hs[36*(4*q+idx) + cl]      = Sv[idx][0]*iz;
    hs[36*(4*q+idx) + cl + 16] = Sv[idx][1]*iz;
  }
  f32x4 p0 = *(const f32x4*)&hs[36*cl + 8*q];
  f32x4 p1 = *(const f32x4*)&hs[36*cl + 8*q + 4];
  bf16x8 Phi, Plo;
  #pragma unroll
  for (int i=0;i<4;i++){
    unsigned short h0 = bfhi(p0[i]);
    Phi[i]   = (short)h0;  Plo[i]   = (short)bfhi(p0[i] - bf2f(h0));
    unsigned short h1 = bfhi(p1[i]);
    Phi[4+i] = (short)h1;  Plo[4+i] = (short)bfhi(p1[i] - bf2f(h1));
  }

  // fc: out[16,32] = pooled[16,32] @ fc_W[32,32] (+b, relu), 2 tiles
  #pragma unroll
  for (int T=0;T<2;T++){
    bf16x8 Fhi, Flo;
    #pragma unroll
    for (int i=0;i<8;i++){
      float wf = fc_W[(size_t)(8*q+i)*H + 16*T + cl];
      unsigned short hh = bfhi(wf);
      Fhi[i] = (short)hh; Flo[i] = (short)bfhi(wf - bf2f(hh));
    }
    float fcbv = fc_b[16*T + cl];
    f32x4 z = {0.f,0.f,0.f,0.f};
    z = __builtin_amdgcn_mfma_f32_16x16x32_bf16(Phi, Flo, z, 0,0,0);
    z = __builtin_amdgcn_mfma_f32_16x16x32_bf16(Plo, Fhi, z, 0,0,0);
    z = __builtin_amdgcn_mfma_f32_16x16x32_bf16(Phi, Fhi, z, 0,0,0);
    #pragma unroll
    for (int idx=0;idx<4;idx++){
      int r = nb + 4*q + idx;
      if (r < N) x1[(size_t)r*H + 16*T + cl] = fmaxf(z[idx] + fcbv, 0.f);
    }
  }
}

// ---------------- GCN helpers (unchanged this round) -----------------------
__global__ void k_deg_init(float* __restrict__ deg, int N){
  int i = blockIdx.x*blockDim.x + threadIdx.x;
  if (i < N) deg[i] = 1.0f;   // self-loop weight
}

__global__ void k_deg_edges(const int* __restrict__ ei, const float* __restrict__ ew,
                            float* __restrict__ deg, int E){
  int e = blockIdx.x*blockDim.x + threadIdx.x;
  if (e < E) atomicAdd(&deg[ei[E+e]], ew[e]);   // dst row = ei[1]
}

__global__ void k_dis(float* __restrict__ deg, int N){
  int i = blockIdx.x*blockDim.x + threadIdx.x;
  if (i < N) deg[i] = __frcp_rn(sqrtf(deg[i]));  // deg >= 1 always
}

__global__ void k_norm(const int* __restrict__ ei, const float* __restrict__ ew,
                       const float* __restrict__ dis, float* __restrict__ nrm, int E){
  int e = blockIdx.x*blockDim.x + threadIdx.x;
  if (e < E) nrm[e] = dis[ei[e]]*ew[e]*dis[ei[E+e]];
}

__global__ __launch_bounds__(256) void k_xw(
    const float* __restrict__ x, const float* __restrict__ W,
    const float* __restrict__ b, const float* __restrict__ dis,
    float* __restrict__ xw, float* __restrict__ out, int N)
{
  int n = blockIdx.x*blockDim.x + threadIdx.x;
  if (n >= N) return;
  float xv[H];
  const float4* xr = (const float4*)(x + (size_t)n*H);
  #pragma unroll
  for (int q=0;q<H/4;q++){
    float4 v = xr[q];
    xv[4*q+0]=v.x; xv[4*q+1]=v.y; xv[4*q+2]=v.z; xv[4*q+3]=v.w;
  }
  float d = dis[n];
  float sn = d*d;               // = 1/deg
  float* xwr = xw + (size_t)n*H;
  float* outr = out + (size_t)n*H;
  #pragma unroll
  for (int j=0;j<H;j++){
    float a = 0.f;
    #pragma unroll
    for (int k=0;k<H;k++) a += xv[k]*W[k*H+j];
    xwr[j]  = a;
    outr[j] = sn*a + b[j];
  }
}

__global__ __launch_bounds__(256) void k_edge(
    const int* __restrict__ ei, const float* __restrict__ nrm,
    const float* __restrict__ xw, float* __restrict__ out, int E)
{
  int tid = blockIdx.x*blockDim.x + threadIdx.x;
  int e = tid >> 3;
  if (e >= E) return;
  int q = (tid & 7) * 4;
  int s = ei[e];
  int d = ei[E+e];
  float nm = nrm[e];
  float4 v = *(const float4*)(xw + (size_t)s*H + q);
  float* o = out + (size_t)d*H + q;
  atomicAdd(o+0, nm*v.x);
  atomicAdd(o+1, nm*v.y);
  atomicAdd(o+2, nm*v.z);
  atomicAdd(o+3, nm*v.w);
}

__global__ void k_final(const float* __restrict__ x2, const float* __restrict__ nx,
                        const float* __restrict__ lw, const float* __restrict__ lb,
                        float* __restrict__ out, int N)
{
  int n = blockIdx.x*blockDim.x + threadIdx.x;
  if (n >= N) return;
  float a = lb[0];
  const float* xr = x2 + (size_t)n*H;
  #pragma unroll
  for (int j=0;j<H;j++) a += xr[j]*lw[j];
  const float* nr = nx + (size_t)n*4;
  #pragma unroll
  for (int f=0;f<4;f++) a += nr[f]*lw[H+f];
  out[n] = fmaxf(a, 0.f);
}

extern "C" void kernel_launch(void* const* d_in, const int* in_sizes, int n_in,
                              void* d_out, int out_size, void* d_ws, size_t ws_size,
                              hipStream_t stream) {
  const float* node_x   = (const float*)d_in[0];
  const float* node_yx  = (const float*)d_in[1];
  const int*   edge_idx = (const int*)  d_in[2];
  const float* edge_w   = (const float*)d_in[3];
  const float* w_ih     = (const float*)d_in[4];
  const float* w_hh     = (const float*)d_in[5];
  const float* b_ih     = (const float*)d_in[6];
  const float* b_hh     = (const float*)d_in[7];
  const float* att_W    = (const float*)d_in[8];
  const float* fc_W     = (const float*)d_in[9];
  const float* fc_b     = (const float*)d_in[10];
  const float* gcn1_W   = (const float*)d_in[11];
  const float* gcn1_b   = (const float*)d_in[12];
  const float* gcn2_W   = (const float*)d_in[13];
  const float* gcn2_b   = (const float*)d_in[14];
  const float* lin_W    = (const float*)d_in[15];
  const float* lin_b    = (const float*)d_in[16];
  float* out = (float*)d_out;

  int N = in_sizes[0] / 4;     // node_x is [N,4]
  int E = in_sizes[3];         // edge_weight is [E]

  float* ws = (float*)d_ws;
  float* x1  = ws;                       // [N,32]  (reused as out2)
  float* xw  = ws + (size_t)N*H;         // [N,32]
  float* o1  = ws + 2*(size_t)N*H;       // [N,32]
  float* deg = ws + 3*(size_t)N*H;       // [N]   (becomes dis)
  float* nrm = deg + N;                  // [E]

  dim3 blk(256);
  int gN  = (N + 255) / 256;
  int gE  = (E + 255) / 256;
  int gE8 = (int)(((size_t)E*8 + 255) / 256);
  int gL  = (N + 15) / 16;               // one 64-thread wave per 16 nodes

  // 1. LSTM + attention + fc (MFMA, wave-local, barrier-free)
  k_lstm<<<gL, dim3(64), 0, stream>>>(node_yx, w_ih, w_hh, b_ih, b_hh,
                                      att_W, fc_W, fc_b, x1, N);
  // 2. degrees (self-loop = 1.0 init), then dis = deg^-1/2, then edge norms
  k_deg_init<<<gN, blk, 0, stream>>>(deg, N);
  k_deg_edges<<<gE, blk, 0, stream>>>(edge_idx, edge_w, deg, E);
  k_dis<<<gN, blk, 0, stream>>>(deg, N);
  k_norm<<<gE, blk, 0, stream>>>(edge_idx, edge_w, deg, nrm, E);
  // 3. GCN layer 1
  k_xw  <<<gN, blk, 0, stream>>>(x1, gcn1_W, gcn1_b, deg, xw, o1, N);
  k_edge<<<gE8, blk, 0, stream>>>(edge_idx, nrm, xw, o1, E);
  // 4. GCN layer 2 (out2 overwrites x1 buffer)
  k_xw  <<<gN, blk, 0, stream>>>(o1, gcn2_W, gcn2_b, deg, xw, x1, N);
  k_edge<<<gE8, blk, 0, stream>>>(edge_idx, nrm, xw, x1, E);
  // 5. final linear + relu
  k_final<<<gN, blk, 0, stream>>>(x1, node_x, lin_W, lin_b, out, N);
}

// Round 6
// 900.820 us; speedup vs baseline: 4.8980x; 2.0133x over previous
//
#include <hip/hip_runtime.h>
#include <math.h>

#define H 32
#define LAGN 50

typedef float f32x4 __attribute__((ext_vector_type(4)));
typedef short bf16x8 __attribute__((ext_vector_type(8)));

__device__ __forceinline__ float rcp_(float x){ return __builtin_amdgcn_rcpf(x); }
__device__ __forceinline__ float sigmoidf_(float x){ return rcp_(1.0f + __expf(-x)); }
__device__ __forceinline__ float tanhf_(float x){ return 1.0f - 2.0f*rcp_(__expf(2.0f*x) + 1.0f); }

// round-to-nearest-even fp32 -> bf16 (bit math, matches MFMA bf16 semantics)
__device__ __forceinline__ unsigned short bfhi(float f){
  unsigned u = __float_as_uint(f);
  return (unsigned short)((u + 0x7FFFu + ((u>>16)&1u)) >> 16);
}
__device__ __forceinline__ float bf2f(unsigned short h){
  return __uint_as_float(((unsigned)h)<<16);
}

// ---------------- MFMA LSTM + time-attention + fc (round 5, unchanged) ------
__global__ __launch_bounds__(64, 2) void k_lstm(
    const float* __restrict__ yx,    // [N,50]
    const float* __restrict__ w_ih,  // [128]
    const float* __restrict__ w_hh,  // [128,32]
    const float* __restrict__ b_ih,  // [128]
    const float* __restrict__ b_hh,  // [128]
    const float* __restrict__ att_W, // [50,32]
    const float* __restrict__ fc_W,  // [32,32]
    const float* __restrict__ fc_b,  // [32]
    float* __restrict__ x1,          // [N,32] out
    int N)
{
  __shared__ float hs[16*36];        // h staging [16 rows][36] (pad: 16B-align + 2-way banks)
  const int l  = threadIdx.x;        // 0..63
  const int q  = l >> 4;             // 0..3
  const int cl = l & 15;             // 0..15
  const int nb = blockIdx.x * 16;    // first node of this wave

  // B fragments of w_hh (hi/lo bf16), held in VGPRs for all 50 steps
  bf16x8 Bhi[8], Blo[8];
  #pragma unroll
  for (int T=0; T<8; ++T){
    const float* p = w_hh + (size_t)(16*T + cl)*H + 8*q;
    f32x4 w0 = *(const f32x4*)p;
    f32x4 w1 = *(const f32x4*)(p+4);
    #pragma unroll
    for (int i=0;i<4;i++){
      unsigned short hh0 = bfhi(w0[i]);
      Bhi[T][i]   = (short)hh0;  Blo[T][i]   = (short)bfhi(w0[i] - bf2f(hh0));
      unsigned short hh1 = bfhi(w1[i]);
      Bhi[T][4+i] = (short)hh1;  Blo[T][4+i] = (short)bfhi(w1[i] - bf2f(hh1));
    }
  }

  float wihv[8], bsv[8];
  #pragma unroll
  for (int T=0;T<8;T++){
    int colg = 16*T + cl;
    wihv[T] = w_ih[colg];
    bsv[T]  = b_ih[colg] + b_hh[colg];
  }

  #pragma unroll
  for (int i=l; i<16*36; i+=64) hs[i] = 0.f;

  float cst[4][2], Sv[4][2], mv[4], Zv[4];
  #pragma unroll
  for (int idx=0;idx<4;idx++){
    mv[idx] = -1e30f; Zv[idx] = 0.f;
    cst[idx][0]=0.f; cst[idx][1]=0.f; Sv[idx][0]=0.f; Sv[idx][1]=0.f;
  }

  float xtc[4], atc[2];
  #pragma unroll
  for (int idx=0;idx<4;idx++){
    int r = nb + 4*q + idx; if (r >= N) r = N-1;
    xtc[idx] = yx[(size_t)r*LAGN];
  }
  atc[0] = att_W[cl];  atc[1] = att_W[cl+16];

  #pragma unroll 1
  for (int t=0;t<LAGN;t++){
    int tn = (t+1<LAGN) ? t+1 : t;
    float xtn[4], atn[2];
    #pragma unroll
    for (int idx=0;idx<4;idx++){
      int r = nb + 4*q + idx; if (r >= N) r = N-1;
      xtn[idx] = yx[(size_t)r*LAGN + tn];
    }
    atn[0] = att_W[tn*H + cl];  atn[1] = att_W[tn*H + cl + 16];

    f32x4 a0 = *(const f32x4*)&hs[36*cl + 8*q];
    f32x4 a1 = *(const f32x4*)&hs[36*cl + 8*q + 4];
    bf16x8 Ahi, Alo;
    #pragma unroll
    for (int i=0;i<4;i++){
      unsigned short h0 = bfhi(a0[i]);
      Ahi[i]   = (short)h0;  Alo[i]   = (short)bfhi(a0[i] - bf2f(h0));
      unsigned short h1 = bfhi(a1[i]);
      Ahi[4+i] = (short)h1;  Alo[4+i] = (short)bfhi(a1[i] - bf2f(h1));
    }

    f32x4 C[8];
    #pragma unroll
    for (int T=0;T<8;T++){
      f32x4 z = {0.f,0.f,0.f,0.f};
      z = __builtin_amdgcn_mfma_f32_16x16x32_bf16(Ahi, Blo[T], z, 0,0,0);
      z = __builtin_amdgcn_mfma_f32_16x16x32_bf16(Alo, Bhi[T], z, 0,0,0);
      z = __builtin_amdgcn_mfma_f32_16x16x32_bf16(Ahi, Bhi[T], z, 0,0,0);
      C[T] = z;
    }

    float stp[4];
    float hv[4][2];
    #pragma unroll
    for (int idx=0; idx<4; ++idx){
      stp[idx] = 0.f;
      #pragma unroll
      for (int jh=0; jh<2; ++jh){
        float gi = C[jh][idx]   + xtc[idx]*wihv[jh]   + bsv[jh];
        float gf = C[2+jh][idx] + xtc[idx]*wihv[2+jh] + bsv[2+jh];
        float gg = C[4+jh][idx] + xtc[idx]*wihv[4+jh] + bsv[4+jh];
        float go = C[6+jh][idx] + xtc[idx]*wihv[6+jh] + bsv[6+jh];
        float iv = sigmoidf_(gi), fv = sigmoidf_(gf);
        float gv = tanhf_(gg),    ov = sigmoidf_(go);
        float cn = fv*cst[idx][jh] + iv*gv;
        cst[idx][jh] = cn;
        float hh = ov*tanhf_(cn);
        hv[idx][jh] = hh;
        stp[idx] += hh * atc[jh];
        hs[36*(4*q+idx) + cl + 16*jh] = hh;
      }
    }

    #pragma unroll
    for (int mask=1; mask<16; mask<<=1){
      #pragma unroll
      for (int idx=0;idx<4;idx++)
        stp[idx] += __shfl_xor(stp[idx], mask);
    }

    #pragma unroll
    for (int idx=0;idx<4;idx++){
      float mn = fmaxf(mv[idx], stp[idx]);
      float sc = __expf(mv[idx] - mn);
      float p  = __expf(stp[idx] - mn);
      Zv[idx] = Zv[idx]*sc + p;
      Sv[idx][0] = Sv[idx][0]*sc + p*hv[idx][0];
      Sv[idx][1] = Sv[idx][1]*sc + p*hv[idx][1];
      mv[idx] = mn;
    }
    #pragma unroll
    for (int idx=0;idx<4;idx++) xtc[idx] = xtn[idx];
    atc[0] = atn[0]; atc[1] = atn[1];
  }

  #pragma unroll
  for (int idx=0;idx<4;idx++){
    float iz = rcp_(Zv[idx]);
    hs[36*(4*q+idx) + cl]      = Sv[idx][0]*iz;
    hs[36*(4*q+idx) + cl + 16] = Sv[idx][1]*iz;
  }
  f32x4 p0 = *(const f32x4*)&hs[36*cl + 8*q];
  f32x4 p1 = *(const f32x4*)&hs[36*cl + 8*q + 4];
  bf16x8 Phi, Plo;
  #pragma unroll
  for (int i=0;i<4;i++){
    unsigned short h0 = bfhi(p0[i]);
    Phi[i]   = (short)h0;  Plo[i]   = (short)bfhi(p0[i] - bf2f(h0));
    unsigned short h1 = bfhi(p1[i]);
    Phi[4+i] = (short)h1;  Plo[4+i] = (short)bfhi(p1[i] - bf2f(h1));
  }

  #pragma unroll
  for (int T=0;T<2;T++){
    bf16x8 Fhi, Flo;
    #pragma unroll
    for (int i=0;i<8;i++){
      float wf = fc_W[(size_t)(8*q+i)*H + 16*T + cl];
      unsigned short hh = bfhi(wf);
      Fhi[i] = (short)hh; Flo[i] = (short)bfhi(wf - bf2f(hh));
    }
    float fcbv = fc_b[16*T + cl];
    f32x4 z = {0.f,0.f,0.f,0.f};
    z = __builtin_amdgcn_mfma_f32_16x16x32_bf16(Phi, Flo, z, 0,0,0);
    z = __builtin_amdgcn_mfma_f32_16x16x32_bf16(Plo, Fhi, z, 0,0,0);
    z = __builtin_amdgcn_mfma_f32_16x16x32_bf16(Phi, Fhi, z, 0,0,0);
    #pragma unroll
    for (int idx=0;idx<4;idx++){
      int r = nb + 4*q + idx;
      if (r < N) x1[(size_t)r*H + 16*T + cl] = fmaxf(z[idx] + fcbv, 0.f);
    }
  }
}

// ---------------- GCN: CSR build (atomic-free feature scatter) --------------
__global__ void k_deg_init(float* __restrict__ deg, int* __restrict__ cnt, int N){
  int i = blockIdx.x*blockDim.x + threadIdx.x;
  if (i < N){ deg[i] = 1.0f; cnt[i] = 0; }   // self-loop weight 1.0
}

__global__ void k_deg_cnt(const int* __restrict__ ei, const float* __restrict__ ew,
                          float* __restrict__ deg, int* __restrict__ cnt, int E){
  int e = blockIdx.x*blockDim.x + threadIdx.x;
  if (e < E){
    int d = ei[E+e];
    atomicAdd(&deg[d], ew[e]);
    atomicAdd(&cnt[d], 1);
  }
}

__global__ void k_dis(float* __restrict__ deg, int N){
  int i = blockIdx.x*blockDim.x + threadIdx.x;
  if (i < N) deg[i] = __frcp_rn(sqrtf(deg[i]));  // deg >= 1 always
}

// exclusive scan of cnt[N] -> rowptr[N+1], pos = rowptr copy.
// single block, 16 waves; wave-shfl scan + cross-wave LDS combine.
__global__ __launch_bounds__(1024) void k_scan(const int* __restrict__ cnt,
                                               int* __restrict__ rowptr,
                                               int* __restrict__ pos, int N){
  __shared__ int wsum[16];
  __shared__ int carry;
  const int tid = threadIdx.x, lane = tid & 63, w = tid >> 6;
  if (tid == 0) carry = 0;
  __syncthreads();
  for (int base = 0; base < N; base += 1024){
    int i = base + tid;
    int v = (i < N) ? cnt[i] : 0;
    int s = v;
    #pragma unroll
    for (int off=1; off<64; off<<=1){
      int t = __shfl_up(s, off);
      if (lane >= off) s += t;
    }
    if (lane == 63) wsum[w] = s;
    __syncthreads();
    int woff = 0, tot = 0;
    #pragma unroll
    for (int k=0;k<16;k++){ int x = wsum[k]; tot += x; if (k < w) woff += x; }
    int excl = carry + woff + s - v;
    if (i < N){ rowptr[i] = excl; pos[i] = excl; }
    __syncthreads();               // everyone read carry before update
    if (tid == 0) carry += tot;
    __syncthreads();
  }
  if (tid == 0) rowptr[N] = carry;
}

// scatter edges into dst-grouped CSR slots; fold norm computation in.
__global__ void k_fill(const int* __restrict__ ei, const float* __restrict__ ew,
                       const float* __restrict__ dis, int* __restrict__ pos,
                       int* __restrict__ csrc, float* __restrict__ cnrm, int E){
  int e = blockIdx.x*blockDim.x + threadIdx.x;
  if (e < E){
    int s = ei[e], d = ei[E+e];
    int slot = atomicAdd(&pos[d], 1);
    csrc[slot] = s;
    cnrm[slot] = dis[s]*ew[e]*dis[d];
  }
}

// xw = x @ W ; out = (1/deg)*xw + b   (self-loop contribution folded in)
__global__ __launch_bounds__(256) void k_xw(
    const float* __restrict__ x, const float* __restrict__ W,
    const float* __restrict__ b, const float* __restrict__ dis,
    float* __restrict__ xw, float* __restrict__ out, int N)
{
  int n = blockIdx.x*blockDim.x + threadIdx.x;
  if (n >= N) return;
  float xv[H];
  const float4* xr = (const float4*)(x + (size_t)n*H);
  #pragma unroll
  for (int q=0;q<H/4;q++){
    float4 v = xr[q];
    xv[4*q+0]=v.x; xv[4*q+1]=v.y; xv[4*q+2]=v.z; xv[4*q+3]=v.w;
  }
  float d = dis[n];
  float sn = d*d;               // = 1/deg
  float* xwr = xw + (size_t)n*H;
  float* outr = out + (size_t)n*H;
  #pragma unroll
  for (int j=0;j<H;j++){
    float a = 0.f;
    #pragma unroll
    for (int k=0;k<H;k++) a += xv[k]*W[k*H+j];
    xwr[j]  = a;
    outr[j] = sn*a + b[j];
  }
}

// atomic-free gather: one wave per dst node; lane = channel x 2-edge pair.
// out[n] (pre-initialized by k_xw with self-loop+bias) += sum_e nrm*xw[src].
__global__ __launch_bounds__(256) void k_gather(
    const int* __restrict__ rowptr, const int* __restrict__ csrc,
    const float* __restrict__ cnrm, const float* __restrict__ xw,
    float* __restrict__ out, int N)
{
  int wid = (int)((blockIdx.x*256u + threadIdx.x) >> 6);   // node = global wave
  if (wid >= N) return;
  int lane = threadIdx.x & 63;
  int ch = lane & 31;
  int eh = lane >> 5;                       // 0/1: even/odd edge
  int start = rowptr[wid], end = rowptr[wid+1];
  float acc = 0.f;
  for (int j = start + eh; j < end; j += 2){
    int s = csrc[j];
    acc += cnrm[j] * xw[(size_t)s*H + ch];
  }
  acc += __shfl_xor(acc, 32);               // combine even/odd halves
  if (eh == 0){
    float* o = out + (size_t)wid*H + ch;
    *o += acc;                              // exclusive owner: plain RMW
  }
}

__global__ void k_final(const float* __restrict__ x2, const float* __restrict__ nx,
                        const float* __restrict__ lw, const float* __restrict__ lb,
                        float* __restrict__ out, int N)
{
  int n = blockIdx.x*blockDim.x + threadIdx.x;
  if (n >= N) return;
  float a = lb[0];
  const float* xr = x2 + (size_t)n*H;
  #pragma unroll
  for (int j=0;j<H;j++) a += xr[j]*lw[j];
  const float* nr = nx + (size_t)n*4;
  #pragma unroll
  for (int f=0;f<4;f++) a += nr[f]*lw[H+f];
  out[n] = fmaxf(a, 0.f);
}

extern "C" void kernel_launch(void* const* d_in, const int* in_sizes, int n_in,
                              void* d_out, int out_size, void* d_ws, size_t ws_size,
                              hipStream_t stream) {
  const float* node_x   = (const float*)d_in[0];
  const float* node_yx  = (const float*)d_in[1];
  const int*   edge_idx = (const int*)  d_in[2];
  const float* edge_w   = (const float*)d_in[3];
  const float* w_ih     = (const float*)d_in[4];
  const float* w_hh     = (const float*)d_in[5];
  const float* b_ih     = (const float*)d_in[6];
  const float* b_hh     = (const float*)d_in[7];
  const float* att_W    = (const float*)d_in[8];
  const float* fc_W     = (const float*)d_in[9];
  const float* fc_b     = (const float*)d_in[10];
  const float* gcn1_W   = (const float*)d_in[11];
  const float* gcn1_b   = (const float*)d_in[12];
  const float* gcn2_W   = (const float*)d_in[13];
  const float* gcn2_b   = (const float*)d_in[14];
  const float* lin_W    = (const float*)d_in[15];
  const float* lin_b    = (const float*)d_in[16];
  float* out = (float*)d_out;

  int N = in_sizes[0] / 4;     // node_x is [N,4]
  int E = in_sizes[3];         // edge_weight is [E]

  float* ws = (float*)d_ws;
  float* x1     = ws;                        // [N*32]
  float* xw     = x1  + (size_t)N*H;         // [N*32]
  float* o1     = xw  + (size_t)N*H;         // [N*32]
  float* deg    = o1  + (size_t)N*H;         // [N] (becomes dis)
  int*   rowptr = (int*)(deg + N);           // [N+1]
  int*   pos    = rowptr + (N+1);            // [N] (cnt during count phase)
  int*   csrc   = pos + N;                   // [E]
  float* cnrm   = (float*)(csrc + E);        // [E]

  dim3 blk(256);
  int gN  = (N + 255) / 256;
  int gE  = (E + 255) / 256;
  int gL  = (N + 15) / 16;                   // one 64-thread wave per 16 nodes
  int gG  = (N + 3) / 4;                     // one wave per node, 4 waves/block

  // 1. LSTM + attention + fc (MFMA, wave-local, barrier-free)
  k_lstm<<<gL, dim3(64), 0, stream>>>(node_yx, w_ih, w_hh, b_ih, b_hh,
                                      att_W, fc_W, fc_b, x1, N);
  // 2. CSR build: deg/count -> dis -> scan -> fill (norm folded into fill)
  k_deg_init<<<gN, blk, 0, stream>>>(deg, pos, N);
  k_deg_cnt <<<gE, blk, 0, stream>>>(edge_idx, edge_w, deg, pos, E);
  k_dis     <<<gN, blk, 0, stream>>>(deg, N);
  k_scan    <<<1, dim3(1024), 0, stream>>>(pos, rowptr, pos, N);
  k_fill    <<<gE, blk, 0, stream>>>(edge_idx, edge_w, deg, pos, csrc, cnrm, E);
  // 3. GCN layer 1: x1 -> (xw) -> o1
  k_xw    <<<gN, blk, 0, stream>>>(x1, gcn1_W, gcn1_b, deg, xw, o1, N);
  k_gather<<<gG, blk, 0, stream>>>(rowptr, csrc, cnrm, xw, o1, N);
  // 4. GCN layer 2: o1 -> (xw) -> x1
  k_xw    <<<gN, blk, 0, stream>>>(o1, gcn2_W, gcn2_b, deg, xw, x1, N);
  k_gather<<<gG, blk, 0, stream>>>(rowptr, csrc, cnrm, xw, x1, N);
  // 5. final linear + relu
  k_final<<<gN, blk, 0, stream>>>(x1, node_x, lin_W, lin_b, out, N);
}

// Round 7
// 772.877 us; speedup vs baseline: 5.7088x; 1.1655x over previous
//
#include <hip/hip_runtime.h>
#include <hip/hip_bf16.h>
#include <stdint.h>
#include <math.h>

#define H 32
#define LAGN 50

typedef float f32x4 __attribute__((ext_vector_type(4)));
typedef short bf16x8 __attribute__((ext_vector_type(8)));

__device__ __forceinline__ float rcp_(float x){ return __builtin_amdgcn_rcpf(x); }
__device__ __forceinline__ float sigmoidf_(float x){ return rcp_(1.0f + __expf(-x)); }
__device__ __forceinline__ float tanhf_(float x){ return 1.0f - 2.0f*rcp_(__expf(2.0f*x) + 1.0f); }

// packed f32x2 -> bf16x2 (RNE) via compiler's v_cvt_pk path
__device__ __forceinline__ unsigned pk_bf2(float f0, float f1){
  union { __hip_bfloat162 b; unsigned u; } cv;
  cv.b = __float22bfloat162_rn(make_float2(f0, f1));
  return cv.u;
}
// 8 floats (two f32x4) -> hi/lo bf16x8 (error-compensated split)
__device__ __forceinline__ void cvt8v(f32x4 a, f32x4 b, bf16x8& hi, bf16x8& lo){
  union U { bf16x8 v; unsigned d[4]; } Hu, Lu;
  #pragma unroll
  for (int p=0;p<2;p++){
    float f0=a[2*p], f1=a[2*p+1];
    unsigned uh = pk_bf2(f0,f1);
    float h0 = __uint_as_float(uh<<16);
    float h1 = __uint_as_float(uh & 0xffff0000u);
    Hu.d[p] = uh;  Lu.d[p] = pk_bf2(f0-h0, f1-h1);
    float g0=b[2*p], g1=b[2*p+1];
    unsigned ug = pk_bf2(g0,g1);
    float k0 = __uint_as_float(ug<<16);
    float k1 = __uint_as_float(ug & 0xffff0000u);
    Hu.d[2+p] = ug;  Lu.d[2+p] = pk_bf2(g0-k0, g1-k1);
  }
  hi = Hu.v; lo = Lu.v;
}

// ---------------- MFMA LSTM + time-attention + fc ---------------------------
// 256-thread blocks = 4 waves x 16 nodes, per-wave private LDS slab, no
// barriers. Bias+input term folded into MFMA accumulator init; softmax
// without online max (scores bounded, exp safe in fp32).
__global__ __launch_bounds__(256, 2) void k_lstm(
    const float* __restrict__ yx,    // [N,50]
    const float* __restrict__ w_ih,  // [128]
    const float* __restrict__ w_hh,  // [128,32]
    const float* __restrict__ b_ih,  // [128]
    const float* __restrict__ b_hh,  // [128]
    const float* __restrict__ att_W, // [50,32]
    const float* __restrict__ fc_W,  // [32,32]
    const float* __restrict__ fc_b,  // [32]
    float* __restrict__ x1,          // [N,32] out
    int N)
{
  __shared__ float hs[4][16*36];     // per-wave slab [16 rows][36]
  const int wv = threadIdx.x >> 6;
  const int l  = threadIdx.x & 63;
  const int q  = l >> 4;
  const int cl = l & 15;
  const int nb = blockIdx.x*64 + wv*16;
  float* HS = hs[wv];

  // B fragments of w_hh (hi/lo bf16), in VGPRs for all 50 steps
  bf16x8 Bhi[8], Blo[8];
  #pragma unroll
  for (int T=0; T<8; ++T){
    const float* p = w_hh + (size_t)(16*T + cl)*H + 8*q;
    f32x4 w0 = *(const f32x4*)p;
    f32x4 w1 = *(const f32x4*)(p+4);
    cvt8v(w0, w1, Bhi[T], Blo[T]);
  }

  float wihv[8], bsv[8];
  #pragma unroll
  for (int T=0;T<8;T++){
    int colg = 16*T + cl;
    wihv[T] = w_ih[colg];
    bsv[T]  = b_ih[colg] + b_hh[colg];
  }

  for (int i=l; i<16*36; i+=64) HS[i] = 0.f;

  float cst[4][2], Sv[4][2], Zv[4];
  #pragma unroll
  for (int idx=0;idx<4;idx++){
    Zv[idx]=0.f; cst[idx][0]=0.f; cst[idx][1]=0.f; Sv[idx][0]=0.f; Sv[idx][1]=0.f;
  }

  const int rr = nb + 4*q;
  const float* yp0 = yx + (size_t)(rr+0<N?rr+0:N-1)*LAGN;
  const float* yp1 = yx + (size_t)(rr+1<N?rr+1:N-1)*LAGN;
  const float* yp2 = yx + (size_t)(rr+2<N?rr+2:N-1)*LAGN;
  const float* yp3 = yx + (size_t)(rr+3<N?rr+3:N-1)*LAGN;

  #pragma unroll 1
  for (int t=0;t<LAGN;t++){
    float xtv[4] = {yp0[t], yp1[t], yp2[t], yp3[t]};
    float at0 = att_W[t*H + cl];
    float at1 = att_W[t*H + cl + 16];

    f32x4 a0 = *(const f32x4*)&HS[36*cl + 8*q];
    f32x4 a1 = *(const f32x4*)&HS[36*cl + 8*q + 4];
    bf16x8 Ahi, Alo;
    cvt8v(a0, a1, Ahi, Alo);

    f32x4 C[8];
    #pragma unroll
    for (int T=0;T<8;T++){
      f32x4 z;
      #pragma unroll
      for (int idx=0;idx<4;idx++) z[idx] = __builtin_fmaf(xtv[idx], wihv[T], bsv[T]);
      z = __builtin_amdgcn_mfma_f32_16x16x32_bf16(Ahi, Blo[T], z, 0,0,0);
      z = __builtin_amdgcn_mfma_f32_16x16x32_bf16(Alo, Bhi[T], z, 0,0,0);
      z = __builtin_amdgcn_mfma_f32_16x16x32_bf16(Ahi, Bhi[T], z, 0,0,0);
      C[T] = z;
    }

    float stp[4], hv[4][2];
    #pragma unroll
    for (int idx=0; idx<4; ++idx){
      stp[idx] = 0.f;
      #pragma unroll
      for (int jh=0; jh<2; ++jh){
        float iv = sigmoidf_(C[jh][idx]);
        float fv = sigmoidf_(C[2+jh][idx]);
        float gv = tanhf_(C[4+jh][idx]);
        float ov = sigmoidf_(C[6+jh][idx]);
        float cn = fv*cst[idx][jh] + iv*gv;
        cst[idx][jh] = cn;
        float hh = ov*tanhf_(cn);
        hv[idx][jh] = hh;
        stp[idx] += hh * (jh ? at1 : at0);
        HS[36*(4*q+idx) + cl + 16*jh] = hh;
      }
    }

    #pragma unroll
    for (int mask=1; mask<16; mask<<=1){
      #pragma unroll
      for (int idx=0;idx<4;idx++)
        stp[idx] += __shfl_xor(stp[idx], mask);
    }

    #pragma unroll
    for (int idx=0;idx<4;idx++){
      float pex = __expf(stp[idx]);   // |st| bounded (~16) -> no max shift needed
      Zv[idx] += pex;
      Sv[idx][0] += pex*hv[idx][0];
      Sv[idx][1] += pex*hv[idx][1];
    }
  }

  #pragma unroll
  for (int idx=0;idx<4;idx++){
    float iz = rcp_(Zv[idx]);
    HS[36*(4*q+idx) + cl]      = Sv[idx][0]*iz;
    HS[36*(4*q+idx) + cl + 16] = Sv[idx][1]*iz;
  }
  f32x4 p0 = *(const f32x4*)&HS[36*cl + 8*q];
  f32x4 p1 = *(const f32x4*)&HS[36*cl + 8*q + 4];
  bf16x8 Phi, Plo;
  cvt8v(p0, p1, Phi, Plo);

  #pragma unroll
  for (int T=0;T<2;T++){
    f32x4 w0, w1;
    #pragma unroll
    for (int i=0;i<4;i++){
      w0[i] = fc_W[(size_t)(8*q+i)*H + 16*T + cl];
      w1[i] = fc_W[(size_t)(8*q+4+i)*H + 16*T + cl];
    }
    bf16x8 Fhi, Flo;
    cvt8v(w0, w1, Fhi, Flo);
    float fcbv = fc_b[16*T + cl];
    f32x4 z = {fcbv, fcbv, fcbv, fcbv};
    z = __builtin_amdgcn_mfma_f32_16x16x32_bf16(Phi, Flo, z, 0,0,0);
    z = __builtin_amdgcn_mfma_f32_16x16x32_bf16(Plo, Fhi, z, 0,0,0);
    z = __builtin_amdgcn_mfma_f32_16x16x32_bf16(Phi, Fhi, z, 0,0,0);
    #pragma unroll
    for (int idx=0;idx<4;idx++){
      int r = nb + 4*q + idx;
      if (r < N) x1[(size_t)r*H + 16*T + cl] = fmaxf(z[idx], 0.f);
    }
  }
}

// ---------------- GCN: CSR build ---------------------------------------------
__global__ void k_deg_init(float* __restrict__ deg, int* __restrict__ cnt, int N){
  int i = blockIdx.x*blockDim.x + threadIdx.x;
  if (i < N){ deg[i] = 1.0f; cnt[i] = 0; }   // self-loop weight 1.0
}

__global__ void k_deg_cnt(const int* __restrict__ ei, const float* __restrict__ ew,
                          float* __restrict__ deg, int* __restrict__ cnt, int E){
  int e = blockIdx.x*blockDim.x + threadIdx.x;
  if (e < E){
    int d = ei[E+e];
    atomicAdd(&deg[d], ew[e]);
    atomicAdd(&cnt[d], 1);
  }
}

__global__ void k_dis(float* __restrict__ deg, int N){
  int i = blockIdx.x*blockDim.x + threadIdx.x;
  if (i < N) deg[i] = __frcp_rn(sqrtf(deg[i]));  // deg >= 1 always
}

// 3-phase parallel scan: block sums -> scan of sums -> per-block scan+offset
__global__ __launch_bounds__(256) void k_scan1(const int* __restrict__ cnt,
                                               int* __restrict__ bsum, int N){
  __shared__ int wsm[4];
  int b = blockIdx.x, t = threadIdx.x;
  int base = b*1024 + t*4;
  int s = 0;
  #pragma unroll
  for (int i=0;i<4;i++) if (base+i < N) s += cnt[base+i];
  #pragma unroll
  for (int off=1; off<64; off<<=1) s += __shfl_xor(s, off);
  if ((t&63) == 0) wsm[t>>6] = s;
  __syncthreads();
  if (t == 0) bsum[b] = wsm[0]+wsm[1]+wsm[2]+wsm[3];
}

__global__ __launch_bounds__(64) void k_scan2(int* __restrict__ bsum, int nb){
  int lane = threadIdx.x;
  int carry = 0;
  for (int base=0; base<nb; base+=64){
    int i = base + lane;
    int v = (i<nb) ? bsum[i] : 0;
    int s = v;
    #pragma unroll
    for (int off=1; off<64; off<<=1){ int tt=__shfl_up(s,off); if (lane>=off) s+=tt; }
    if (i<nb) bsum[i] = carry + s - v;
    carry += __shfl(s, 63);
  }
}

__global__ __launch_bounds__(256) void k_scan3(int* cp,       // cnt in, start out
                                               const int* __restrict__ bsum,
                                               int* __restrict__ rowptr, int N){
  __shared__ int wsm[4];
  int b = blockIdx.x, t = threadIdx.x, lane = t&63, w = t>>6;
  int base = b*1024 + t*4;
  int v[4];
  #pragma unroll
  for (int i=0;i<4;i++) v[i] = (base+i<N) ? cp[base+i] : 0;
  int tsum = v[0]+v[1]+v[2]+v[3];
  int s = tsum;
  #pragma unroll
  for (int off=1; off<64; off<<=1){ int tt=__shfl_up(s,off); if (lane>=off) s+=tt; }
  if (lane==63) wsm[w] = s;
  __syncthreads();
  int woff = 0;
  #pragma unroll
  for (int k=0;k<4;k++) if (k<w) woff += wsm[k];
  int e = bsum[b] + woff + (s - tsum);
  #pragma unroll
  for (int i=0;i<4;i++){
    if (base+i < N){ rowptr[base+i] = e; cp[base+i] = e; }
    if (base+i == N-1) rowptr[N] = e + v[i];
    e += v[i];
  }
}

// scatter edges into dst-grouped CSR slots, {src, norm} fused in one int2
__global__ void k_fill(const int* __restrict__ ei, const float* __restrict__ ew,
                       const float* __restrict__ dis, int* __restrict__ pos,
                       int2* __restrict__ cedge, int E){
  int e = blockIdx.x*blockDim.x + threadIdx.x;
  if (e < E){
    int s = ei[e], d = ei[E+e];
    int slot = atomicAdd(&pos[d], 1);
    cedge[slot] = make_int2(s, __float_as_int(dis[s]*ew[e]*dis[d]));
  }
}

// xw = x @ W ; out = (1/deg)*xw + b   (self-loop contribution folded in)
__global__ __launch_bounds__(256) void k_xw(
    const float* __restrict__ x, const float* __restrict__ W,
    const float* __restrict__ b, const float* __restrict__ dis,
    float* __restrict__ xw, float* __restrict__ out, int N)
{
  int n = blockIdx.x*blockDim.x + threadIdx.x;
  if (n >= N) return;
  float xv[H];
  const float4* xr = (const float4*)(x + (size_t)n*H);
  #pragma unroll
  for (int q=0;q<H/4;q++){
    float4 v = xr[q];
    xv[4*q+0]=v.x; xv[4*q+1]=v.y; xv[4*q+2]=v.z; xv[4*q+3]=v.w;
  }
  float d = dis[n];
  float sn = d*d;               // = 1/deg
  float* xwr = xw + (size_t)n*H;
  float* outr = out + (size_t)n*H;
  #pragma unroll
  for (int j=0;j<H;j++){
    float a = 0.f;
    #pragma unroll
    for (int k=0;k<H;k++) a += xv[k]*W[k*H+j];
    xwr[j]  = a;
    outr[j] = sn*a + b[j];
  }
}

// atomic-free gather: one wave per dst node; lane = channel x 2-edge pair
__global__ __launch_bounds__(256) void k_gather(
    const int* __restrict__ rowptr, const int2* __restrict__ cedge,
    const float* __restrict__ xw, float* __restrict__ out, int N)
{
  int wid = (int)((blockIdx.x*256u + threadIdx.x) >> 6);
  if (wid >= N) return;
  int lane = threadIdx.x & 63;
  int ch = lane & 31;
  int eh = lane >> 5;
  int start = rowptr[wid], end = rowptr[wid+1];
  float acc = 0.f;
  for (int j = start + eh; j < end; j += 2){
    int2 e = cedge[j];
    acc += __int_as_float(e.y) * xw[(size_t)e.x*H + ch];
  }
  acc += __shfl_xor(acc, 32);
  if (eh == 0){
    float* o = out + (size_t)wid*H + ch;
    *o += acc;
  }
}

__global__ void k_final(const float* __restrict__ x2, const float* __restrict__ nx,
                        const float* __restrict__ lw, const float* __restrict__ lb,
                        float* __restrict__ out, int N)
{
  int n = blockIdx.x*blockDim.x + threadIdx.x;
  if (n >= N) return;
  float a = lb[0];
  const float* xr = x2 + (size_t)n*H;
  #pragma unroll
  for (int j=0;j<H;j++) a += xr[j]*lw[j];
  const float* nr = nx + (size_t)n*4;
  #pragma unroll
  for (int f=0;f<4;f++) a += nr[f]*lw[H+f];
  out[n] = fmaxf(a, 0.f);
}

extern "C" void kernel_launch(void* const* d_in, const int* in_sizes, int n_in,
                              void* d_out, int out_size, void* d_ws, size_t ws_size,
                              hipStream_t stream) {
  const float* node_x   = (const float*)d_in[0];
  const float* node_yx  = (const float*)d_in[1];
  const int*   edge_idx = (const int*)  d_in[2];
  const float* edge_w   = (const float*)d_in[3];
  const float* w_ih     = (const float*)d_in[4];
  const float* w_hh     = (const float*)d_in[5];
  const float* b_ih     = (const float*)d_in[6];
  const float* b_hh     = (const float*)d_in[7];
  const float* att_W    = (const float*)d_in[8];
  const float* fc_W     = (const float*)d_in[9];
  const float* fc_b     = (const float*)d_in[10];
  const float* gcn1_W   = (const float*)d_in[11];
  const float* gcn1_b   = (const float*)d_in[12];
  const float* gcn2_W   = (const float*)d_in[13];
  const float* gcn2_b   = (const float*)d_in[14];
  const float* lin_W    = (const float*)d_in[15];
  const float* lin_b    = (const float*)d_in[16];
  float* out = (float*)d_out;

  int N = in_sizes[0] / 4;     // node_x is [N,4]
  int E = in_sizes[3];         // edge_weight is [E]

  float* ws = (float*)d_ws;
  float* x1     = ws;                        // [N*32]
  float* xw     = x1  + (size_t)N*H;         // [N*32]
  float* o1     = xw  + (size_t)N*H;         // [N*32]
  float* deg    = o1  + (size_t)N*H;         // [N] (becomes dis)
  int*   rowptr = (int*)(deg + N);           // [N+1]
  int*   pos    = rowptr + (N+1);            // [N] (cnt -> start)
  uintptr_t ca  = ((uintptr_t)(pos + N) + 7) & ~(uintptr_t)7;
  int2*  cedge  = (int2*)ca;                 // [E] {src, norm}
  int*   bsum   = (int*)(cedge + E);         // [ceil(N/1024)]

  dim3 blk(256);
  int gN  = (N + 255) / 256;
  int gE  = (E + 255) / 256;
  int gL  = (N + 63) / 64;                   // 64 nodes per 256-thread block
  int gG  = (N + 3) / 4;                     // one wave per node
  int gS  = (N + 1023) / 1024;               // scan blocks

  // 1. LSTM + attention + fc (MFMA, 4 waves/block, barrier-free)
  k_lstm<<<gL, blk, 0, stream>>>(node_yx, w_ih, w_hh, b_ih, b_hh,
                                 att_W, fc_W, fc_b, x1, N);
  // 2. CSR build: deg/count -> dis -> 3-phase scan -> fill
  k_deg_init<<<gN, blk, 0, stream>>>(deg, pos, N);
  k_deg_cnt <<<gE, blk, 0, stream>>>(edge_idx, edge_w, deg, pos, E);
  k_dis     <<<gN, blk, 0, stream>>>(deg, N);
  k_scan1   <<<gS, blk, 0, stream>>>(pos, bsum, N);
  k_scan2   <<<1, dim3(64), 0, stream>>>(bsum, gS);
  k_scan3   <<<gS, blk, 0, stream>>>(pos, bsum, rowptr, N);
  k_fill    <<<gE, blk, 0, stream>>>(edge_idx, edge_w, deg, pos, cedge, E);
  // 3. GCN layer 1: x1 -> (xw) -> o1
  k_xw    <<<gN, blk, 0, stream>>>(x1, gcn1_W, gcn1_b, deg, xw, o1, N);
  k_gather<<<gG, blk, 0, stream>>>(rowptr, cedge, xw, o1, N);
  // 4. GCN layer 2: o1 -> (xw) -> x1
  k_xw    <<<gN, blk, 0, stream>>>(o1, gcn2_W, gcn2_b, deg, xw, x1, N);
  k_gather<<<gG, blk, 0, stream>>>(rowptr, cedge, xw, x1, N);
  // 5. final linear + relu
  k_final<<<gN, blk, 0, stream>>>(x1, node_x, lin_W, lin_b, out, N);
}